// Round 13
// baseline (674.334 us; speedup 1.0000x reference)
//
#include <hip/hip_runtime.h>
#include <hip/hip_cooperative_groups.h>

namespace cg = cooperative_groups;

typedef __attribute__((ext_vector_type(8))) short short8;
typedef __attribute__((ext_vector_type(4))) float float4v;

#define NNODES 8192
#define SEQLEN 256

static __device__ __forceinline__ float bf2f(unsigned short u) {
  union { unsigned u; float f; } v; v.u = ((unsigned)u) << 16; return v.f;
}
static __device__ __forceinline__ unsigned short f2bf(float f) {
  union { float f; unsigned u; } v; v.f = f;
  unsigned r = v.u + 0x7FFFu + ((v.u >> 16) & 1u);
  return (unsigned short)(r >> 16);
}
static __device__ __forceinline__ void splitbf8(const float* v, short8& hi) {
#pragma unroll
  for (int j = 0; j < 8; ++j) hi[j] = (short)f2bf(v[j]);
}
// LSTM cell, log2-prescaled gates, merged-rcp: 5 exp2 + 3 rcp.
static __device__ __forceinline__ float lstm_cell(float zi, float zf, float zg,
                                                  float zo, float& c) {
  float ef = __builtin_amdgcn_exp2f(-zf);
  float ei = __builtin_amdgcn_exp2f(-zi);
  float eg = __builtin_amdgcn_exp2f(fminf(zg + zg, 60.f));
  float fterm = c * __builtin_amdgcn_rcpf(1.f + ef);
  float igt = (eg - 1.f) * __builtin_amdgcn_rcpf((1.f + ei) * (eg + 1.f));
  c = fterm + igt;
  float eo = __builtin_amdgcn_exp2f(-zo);
  float ec = __builtin_amdgcn_exp2f(fminf(2.88539008178f * c, 40.f));
  return (ec - 1.f) * __builtin_amdgcn_rcpf((1.f + eo) * (ec + 1.f));
}

struct MArgs {
  const float *x, *Wih1, *Whh1, *bih1, *bhh1, *ln_g, *ln_b, *Wih2, *Whh2, *bih2, *bhh2;
  const float *Wg1, *bg1, *Wg2, *bg2, *Wfc, *bfc, *ew;
  const int* ei;
  unsigned long long* pk;
  float *dinv, *h2o, *hWa, *aggB, *out;
  int *off, *pos;
  int2* ed;
  int E;
};

// v13 mega: LSTM + count + scan + scatter + gather_mid + gather_final,
// cooperative grid syncs between global phases.
__global__ __launch_bounds__(512, 4) void mega_k(MArgs a) {
  cg::grid_group grid = cg::this_grid();
  const int tid = threadIdx.x;
  const int w = tid >> 6;
  const int lane = tid & 63;
  const int c = lane & 15;
  const int q = lane >> 4;
  const int cn = lane >> 2;
  const int ch = lane & 3;
  const int hid = w * 4 + ch;
  const int nodeBase = blockIdx.x * 16;
  const float L = 1.44269504089f;

  __shared__ __align__(16) float xlds[16 * 260];
  __shared__ __align__(16) float zbuf1[16 * 132];
  __shared__ __align__(16) float zbuf2[16 * 132];
  __shared__ __align__(16) unsigned short h1p[2][16 * 40];
  __shared__ __align__(16) unsigned short h2p[2][16 * 40];
  __shared__ __align__(16) float mu2[32];
  __shared__ __align__(16) float wgbuf[32 * 33];   // Wg1 in P1, Wg2 in P4
  __shared__ __align__(16) float h2f[16 * 33];     // h2 in P1, g1buf in P4
  __shared__ int wtot[8], wexcl[8];

  // =================== P1: LSTM ===================
  for (int i = tid; i < 16 * 256; i += 512) {
    int nn = i >> 8, tt = i & 255;
    xlds[nn * 260 + tt] = a.x[(size_t)(nodeBase + nn) * SEQLEN + tt];
  }
  if (tid < 64) xlds[(tid >> 2) * 260 + 256 + (tid & 3)] = 0.f;
  for (int i = tid; i < 1024; i += 512) wgbuf[(i >> 5) * 33 + (i & 31)] = a.Wg1[i];

  const int brow = (c & 3) * 32 + w * 4 + (c >> 2);
  short8 Bh1, Bi2, Bh2;
  float Gpre, b1pre, b2pre;
  {
    float v[8];
#pragma unroll
    for (int j = 0; j < 8; ++j) v[j] = L * a.Whh1[brow * 32 + q * 8 + j];
    splitbf8(v, Bh1);
#pragma unroll
    for (int j = 0; j < 8; ++j) v[j] = L * a.Wih2[brow * 32 + q * 8 + j] * a.ln_g[q * 8 + j];
    splitbf8(v, Bi2);
#pragma unroll
    for (int j = 0; j < 8; ++j) v[j] = L * a.Whh2[brow * 32 + q * 8 + j];
    splitbf8(v, Bh2);
    float sG = 0.f, sB = 0.f;
    for (int k = 0; k < 32; ++k) {
      sG += a.Wih2[brow * 32 + k] * a.ln_g[k];
      sB += a.Wih2[brow * 32 + k] * a.ln_b[k];
    }
    Gpre = L * sG;
    b1pre = L * (a.bih1[brow] + a.bhh1[brow]);
    b2pre = L * (sB + a.bih2[brow] + a.bhh2[brow]);
  }
  const float4v C1 = {b1pre, b1pre, b1pre, b1pre};
  const float4v C2 = {b2pre, b2pre, b2pre, b2pre};
  const float4v z4 = {0.f, 0.f, 0.f, 0.f};
  float w1v[4];
#pragma unroll
  for (int g = 0; g < 4; ++g) w1v[g] = L * a.Wih1[g * 32 + hid];

  int zW[4];
#pragma unroll
  for (int r = 0; r < 4; ++r) zW[r] = (q * 4 + r) * 132 + w * 16 + c;
  const int zR = cn * 132 + hid * 4;
  const int hWr = cn * 40 + hid;
  const int hRd = c * 40 + q * 8;

  short8 h1A = {0,0,0,0,0,0,0,0};
  short8 h2A = {0,0,0,0,0,0,0,0};
  float c1 = 0.f, c2 = 0.f, hv2 = 0.f;
  __syncthreads();

  {
    float4v za = __builtin_amdgcn_mfma_f32_16x16x32_bf16(h1A, Bh1, C1, 0, 0, 0);
#pragma unroll
    for (int r = 0; r < 4; ++r) zbuf1[zW[r]] = za[r];
    float4v zv = *(const float4v*)&zbuf1[zR];
    float xv = xlds[cn * 260 + 0];
    float hv = lstm_cell(fmaf(xv, w1v[0], zv[0]), fmaf(xv, w1v[1], zv[1]),
                         fmaf(xv, w1v[2], zv[2]), fmaf(xv, w1v[3], zv[3]), c1);
    h1p[1][hWr] = f2bf(hv);
  }
  __syncthreads();
  h1A = *(const short8*)&h1p[1][hRd];

  for (int t = 0; t < SEQLEN; ++t) {
    const int pl = t & 1;
    float4v za = __builtin_amdgcn_mfma_f32_16x16x32_bf16(h1A, Bh1, C1, 0, 0, 0);
    float4v db = __builtin_amdgcn_mfma_f32_16x16x32_bf16(h2A, Bh2, C2, 0, 0, 0);

    float s = 0.f, s2 = 0.f;
#pragma unroll
    for (int j = 0; j < 8; ++j) {
      float hf = bf2f((unsigned short)h1A[j]);
      s += hf; s2 = fmaf(hf, hf, s2);
    }
    s  += __shfl_xor(s, 16, 64);  s  += __shfl_xor(s, 32, 64);
    s2 += __shfl_xor(s2, 16, 64); s2 += __shfl_xor(s2, 32, 64);
    float mu = s * (1.f / 32.f);
    float var = s2 * (1.f / 32.f) - mu * mu;
    float rstd = rsqrtf(var + 1e-5f);
    if (q < 2) mu2[c * 2 + q] = (q == 0) ? rstd : rstd * mu;

    float4v da = __builtin_amdgcn_mfma_f32_16x16x32_bf16(h1A, Bi2, z4, 0, 0, 0);
#pragma unroll
    for (int r = 0; r < 4; ++r) {
      float2 ab = *(const float2*)&mu2[(q * 4 + r) * 2];
      zbuf2[zW[r]] = fmaf(ab.x, da[r], fmaf(-ab.y, Gpre, db[r]));
      zbuf1[zW[r]] = za[r];
    }
    {
      float4v zv = *(const float4v*)&zbuf2[zR];
      hv2 = lstm_cell(zv[0], zv[1], zv[2], zv[3], c2);
      h2p[pl][hWr] = f2bf(hv2);
    }
    {
      float4v zv = *(const float4v*)&zbuf1[zR];
      float xv = xlds[cn * 260 + t + 1];
      float hv = lstm_cell(fmaf(xv, w1v[0], zv[0]), fmaf(xv, w1v[1], zv[1]),
                           fmaf(xv, w1v[2], zv[2]), fmaf(xv, w1v[3], zv[3]), c1);
      h1p[pl][hWr] = f2bf(hv);
    }
    __syncthreads();
    h1A = *(const short8*)&h1p[pl][hRd];
    h2A = *(const short8*)&h2p[pl][hRd];
  }

  a.h2o[(size_t)(nodeBase + cn) * 32 + hid] = hv2;

  __syncthreads();
  h2f[cn * 33 + hid] = hv2;
  __syncthreads();
  {
    int nl = tid >> 5, j = tid & 31;
    float acc = 0.f;
#pragma unroll
    for (int k = 0; k < 32; ++k) acc = fmaf(h2f[nl * 33 + k], wgbuf[k * 33 + j], acc);
    a.hWa[(size_t)(nodeBase + nl) * 32 + j] = acc;
  }

  // =================== P1b: edge count (post-loop; drains in sync shadow) ==
  {
    int e = blockIdx.x * 512 + tid;
    if (e < a.E) {
      int d = a.ei[a.E + e];
      unsigned long long pay = (1ull << 40) |
          (unsigned long long)(unsigned)(a.ew[e] * 16777216.f + 0.5f);
      atomicAdd(&a.pk[d], pay);
    }
  }
  grid.sync();

  // =================== P2: scan (block 0, 512 thr x 16 buckets) ============
  if (blockIdx.x == 0) {
    int base = tid * 16;
    int v[16]; int sum = 0;
#pragma unroll
    for (int i = 0; i < 16; ++i) {
      unsigned long long u = a.pk[base + i];
      v[i] = (int)(u >> 40);
      float degv = (float)(u & 0xFFFFFFFFFFull) * (1.f / 16777216.f);
      a.dinv[base + i] = rsqrtf(degv + 1.0f);
      sum += v[i];
    }
    int incl = sum;
#pragma unroll
    for (int d = 1; d < 64; d <<= 1) {
      int t = __shfl_up(incl, d, 64);
      if (lane >= d) incl += t;
    }
    if (lane == 63) wtot[w] = incl;
    __syncthreads();
    if (w == 0 && lane < 8) {
      int wval = wtot[lane];
      int wincl = wval;
#pragma unroll
      for (int d = 1; d < 8; d <<= 1) {
        int t = __shfl_up(wincl, d, 64);
        if (lane >= d) wincl += t;
      }
      wexcl[lane] = wincl - wval;
    }
    __syncthreads();
    int run = wexcl[w] + (incl - sum);
#pragma unroll
    for (int i = 0; i < 16; ++i) {
      a.off[base + i] = run; a.pos[base + i] = run; run += v[i];
    }
    if (tid == 511) a.off[8192] = run;
  }
  grid.sync();

  // =================== P3: scatter ==========================================
  {
    int e = blockIdx.x * 512 + tid;
    if (e < a.E) {
      int sidx = a.ei[e], d = a.ei[a.E + e];
      int p = atomicAdd(&a.pos[d], 1);
      int2 pay;
      pay.x = sidx;
      pay.y = __float_as_int(a.dinv[sidx] * a.ew[e] * a.dinv[d]);
      a.ed[p] = pay;
    }
  }
  grid.sync();

  // =================== P4: conv1 gather + elu + (g1 @ Wg2) =================
  {
    for (int i = tid; i < 1024; i += 512) wgbuf[(i >> 5) * 33 + (i & 31)] = a.Wg2[i];
    int nl = tid >> 5, j = tid & 31;
    int node = blockIdx.x * 16 + nl;
    float dv = a.dinv[node];
    float a0 = dv * dv * a.hWa[(size_t)node * 32 + j];
    float a1 = 0.f, a2 = 0.f, a3 = 0.f;
    int p0 = a.off[node], p1 = a.off[node + 1];
    int p = p0;
    for (; p + 3 < p1; p += 4) {
      int2 e0 = a.ed[p], e1 = a.ed[p + 1], e2 = a.ed[p + 2], e3 = a.ed[p + 3];
      a0 = fmaf(__int_as_float(e0.y), a.hWa[(size_t)e0.x * 32 + j], a0);
      a1 = fmaf(__int_as_float(e1.y), a.hWa[(size_t)e1.x * 32 + j], a1);
      a2 = fmaf(__int_as_float(e2.y), a.hWa[(size_t)e2.x * 32 + j], a2);
      a3 = fmaf(__int_as_float(e3.y), a.hWa[(size_t)e3.x * 32 + j], a3);
    }
    for (; p < p1; ++p) {
      int2 e0 = a.ed[p];
      a0 = fmaf(__int_as_float(e0.y), a.hWa[(size_t)e0.x * 32 + j], a0);
    }
    float v = (a0 + a1) + (a2 + a3) + a.bg1[j];
    h2f[nl * 33 + j] = (v > 0.f) ? v : expm1f(v);   // g1buf overlay
    __syncthreads();
    float acc = 0.f;
#pragma unroll
    for (int k = 0; k < 32; ++k) acc = fmaf(h2f[nl * 33 + k], wgbuf[k * 33 + j], acc);
    a.aggB[(size_t)node * 32 + j] = acc;
  }
  grid.sync();

  // =================== P5: conv2 gather + elu + mean + fc + log-softmax ====
  {
    int nl = tid >> 5, j = tid & 31;
    int node = blockIdx.x * 16 + nl;
    float dv = a.dinv[node];
    float a0 = dv * dv * a.aggB[(size_t)node * 32 + j];
    float a1 = 0.f, a2 = 0.f, a3 = 0.f;
    int p0 = a.off[node], p1 = a.off[node + 1];
    int p = p0;
    for (; p + 3 < p1; p += 4) {
      int2 e0 = a.ed[p], e1 = a.ed[p + 1], e2 = a.ed[p + 2], e3 = a.ed[p + 3];
      a0 = fmaf(__int_as_float(e0.y), a.aggB[(size_t)e0.x * 32 + j], a0);
      a1 = fmaf(__int_as_float(e1.y), a.aggB[(size_t)e1.x * 32 + j], a1);
      a2 = fmaf(__int_as_float(e2.y), a.aggB[(size_t)e2.x * 32 + j], a2);
      a3 = fmaf(__int_as_float(e3.y), a.aggB[(size_t)e3.x * 32 + j], a3);
    }
    for (; p < p1; ++p) {
      int2 e0 = a.ed[p];
      a0 = fmaf(__int_as_float(e0.y), a.aggB[(size_t)e0.x * 32 + j], a0);
    }
    float v = (a0 + a1) + (a2 + a3) + a.bg2[j];
    float e = (v > 0.f) ? v : expm1f(v);
    float h2v = a.h2o[(size_t)node * 32 + j];
    float p0s = h2v * a.Wfc[j];
    float p1s = h2v * a.Wfc[33 + j];
#pragma unroll
    for (int m = 1; m < 32; m <<= 1) {
      e   += __shfl_xor(e, m, 32);
      p0s += __shfl_xor(p0s, m, 32);
      p1s += __shfl_xor(p1s, m, 32);
    }
    if (j == 0) {
      float mean = e * (1.f / 32.f);
      float o0 = p0s + mean * a.Wfc[32] + a.bfc[0];
      float o1 = p1s + mean * a.Wfc[65] + a.bfc[1];
      float mx = fmaxf(o0, o1);
      float l = mx + logf(expf(o0 - mx) + expf(o1 - mx));
      a.out[node * 2 + 0] = o0 - l;
      a.out[node * 2 + 1] = o1 - l;
    }
  }
}

// ======================= fallback path (v12 kernels) ========================
__global__ __launch_bounds__(512, 4)
void lstm_fused(const float* __restrict__ x,
                const float* __restrict__ Wih1, const float* __restrict__ Whh1,
                const float* __restrict__ bih1, const float* __restrict__ bhh1,
                const float* __restrict__ ln_g, const float* __restrict__ ln_b,
                const float* __restrict__ Wih2, const float* __restrict__ Whh2,
                const float* __restrict__ bih2, const float* __restrict__ bhh2,
                const float* __restrict__ Wg1,
                float* __restrict__ h2out, float* __restrict__ hWa)
{
  const int tid = threadIdx.x;
  const int w = tid >> 6;
  const int lane = tid & 63;
  const int c = lane & 15;
  const int q = lane >> 4;
  const int cn = lane >> 2;
  const int ch = lane & 3;
  const int hid = w * 4 + ch;
  const int nodeBase = blockIdx.x * 16;
  const float L = 1.44269504089f;

  __shared__ __align__(16) float xlds[16 * 260];
  __shared__ __align__(16) float zbuf1[16 * 132];
  __shared__ __align__(16) float zbuf2[16 * 132];
  __shared__ __align__(16) unsigned short h1p[2][16 * 40];
  __shared__ __align__(16) unsigned short h2p[2][16 * 40];
  __shared__ __align__(16) float mu2[32];
  __shared__ __align__(16) float wgbuf[32 * 33];
  __shared__ __align__(16) float h2f[16 * 33];

  for (int i = tid; i < 16 * 256; i += 512) {
    int nn = i >> 8, tt = i & 255;
    xlds[nn * 260 + tt] = x[(size_t)(nodeBase + nn) * SEQLEN + tt];
  }
  if (tid < 64) xlds[(tid >> 2) * 260 + 256 + (tid & 3)] = 0.f;
  for (int i = tid; i < 1024; i += 512) wgbuf[(i >> 5) * 33 + (i & 31)] = Wg1[i];

  const int brow = (c & 3) * 32 + w * 4 + (c >> 2);
  short8 Bh1, Bi2, Bh2;
  float Gpre, b1pre, b2pre;
  {
    float v[8];
#pragma unroll
    for (int j = 0; j < 8; ++j) v[j] = L * Whh1[brow * 32 + q * 8 + j];
    splitbf8(v, Bh1);
#pragma unroll
    for (int j = 0; j < 8; ++j) v[j] = L * Wih2[brow * 32 + q * 8 + j] * ln_g[q * 8 + j];
    splitbf8(v, Bi2);
#pragma unroll
    for (int j = 0; j < 8; ++j) v[j] = L * Whh2[brow * 32 + q * 8 + j];
    splitbf8(v, Bh2);
    float sG = 0.f, sB = 0.f;
    for (int k = 0; k < 32; ++k) {
      sG += Wih2[brow * 32 + k] * ln_g[k];
      sB += Wih2[brow * 32 + k] * ln_b[k];
    }
    Gpre = L * sG;
    b1pre = L * (bih1[brow] + bhh1[brow]);
    b2pre = L * (sB + bih2[brow] + bhh2[brow]);
  }
  const float4v C1 = {b1pre, b1pre, b1pre, b1pre};
  const float4v C2 = {b2pre, b2pre, b2pre, b2pre};
  const float4v z4 = {0.f, 0.f, 0.f, 0.f};
  float w1v[4];
#pragma unroll
  for (int g = 0; g < 4; ++g) w1v[g] = L * Wih1[g * 32 + hid];

  int zW[4];
#pragma unroll
  for (int r = 0; r < 4; ++r) zW[r] = (q * 4 + r) * 132 + w * 16 + c;
  const int zR = cn * 132 + hid * 4;
  const int hWr = cn * 40 + hid;
  const int hRd = c * 40 + q * 8;

  short8 h1A = {0,0,0,0,0,0,0,0};
  short8 h2A = {0,0,0,0,0,0,0,0};
  float c1 = 0.f, c2 = 0.f, hv2 = 0.f;
  __syncthreads();

  {
    float4v za = __builtin_amdgcn_mfma_f32_16x16x32_bf16(h1A, Bh1, C1, 0, 0, 0);
#pragma unroll
    for (int r = 0; r < 4; ++r) zbuf1[zW[r]] = za[r];
    float4v zv = *(const float4v*)&zbuf1[zR];
    float xv = xlds[cn * 260 + 0];
    float hv = lstm_cell(fmaf(xv, w1v[0], zv[0]), fmaf(xv, w1v[1], zv[1]),
                         fmaf(xv, w1v[2], zv[2]), fmaf(xv, w1v[3], zv[3]), c1);
    h1p[1][hWr] = f2bf(hv);
  }
  __syncthreads();
  h1A = *(const short8*)&h1p[1][hRd];

  for (int t = 0; t < SEQLEN; ++t) {
    const int pl = t & 1;
    float4v za = __builtin_amdgcn_mfma_f32_16x16x32_bf16(h1A, Bh1, C1, 0, 0, 0);
    float4v db = __builtin_amdgcn_mfma_f32_16x16x32_bf16(h2A, Bh2, C2, 0, 0, 0);

    float s = 0.f, s2 = 0.f;
#pragma unroll
    for (int j = 0; j < 8; ++j) {
      float hf = bf2f((unsigned short)h1A[j]);
      s += hf; s2 = fmaf(hf, hf, s2);
    }
    s  += __shfl_xor(s, 16, 64);  s  += __shfl_xor(s, 32, 64);
    s2 += __shfl_xor(s2, 16, 64); s2 += __shfl_xor(s2, 32, 64);
    float mu = s * (1.f / 32.f);
    float var = s2 * (1.f / 32.f) - mu * mu;
    float rstd = rsqrtf(var + 1e-5f);
    if (q < 2) mu2[c * 2 + q] = (q == 0) ? rstd : rstd * mu;

    float4v da = __builtin_amdgcn_mfma_f32_16x16x32_bf16(h1A, Bi2, z4, 0, 0, 0);
#pragma unroll
    for (int r = 0; r < 4; ++r) {
      float2 ab = *(const float2*)&mu2[(q * 4 + r) * 2];
      zbuf2[zW[r]] = fmaf(ab.x, da[r], fmaf(-ab.y, Gpre, db[r]));
      zbuf1[zW[r]] = za[r];
    }
    {
      float4v zv = *(const float4v*)&zbuf2[zR];
      hv2 = lstm_cell(zv[0], zv[1], zv[2], zv[3], c2);
      h2p[pl][hWr] = f2bf(hv2);
    }
    {
      float4v zv = *(const float4v*)&zbuf1[zR];
      float xv = xlds[cn * 260 + t + 1];
      float hv = lstm_cell(fmaf(xv, w1v[0], zv[0]), fmaf(xv, w1v[1], zv[1]),
                           fmaf(xv, w1v[2], zv[2]), fmaf(xv, w1v[3], zv[3]), c1);
      h1p[pl][hWr] = f2bf(hv);
    }
    __syncthreads();
    h1A = *(const short8*)&h1p[pl][hRd];
    h2A = *(const short8*)&h2p[pl][hRd];
  }

  h2out[(size_t)(nodeBase + cn) * 32 + hid] = hv2;

  __syncthreads();
  h2f[cn * 33 + hid] = hv2;
  __syncthreads();
  {
    int nl = tid >> 5, j = tid & 31;
    float acc = 0.f;
#pragma unroll
    for (int k = 0; k < 32; ++k) acc = fmaf(h2f[nl * 33 + k], wgbuf[k * 33 + j], acc);
    hWa[(size_t)(nodeBase + nl) * 32 + j] = acc;
  }
}

__global__ void count_k(const int* __restrict__ ei, const float* __restrict__ ew,
                        unsigned long long* __restrict__ pk, int E) {
  int e = blockIdx.x * 256 + threadIdx.x;
  if (e >= E) return;
  int d = ei[E + e];
  unsigned long long pay = (1ull << 40) |
      (unsigned long long)(unsigned)(ew[e] * 16777216.f + 0.5f);
  atomicAdd(&pk[d], pay);
}

__global__ __launch_bounds__(1024, 1)
void scan_k(const unsigned long long* __restrict__ pk, int* __restrict__ off,
            int* __restrict__ pos, float* __restrict__ dinv) {
  __shared__ int wtot[16];
  __shared__ int wexcl[16];
  int tid = threadIdx.x;
  int wv = tid >> 6, lane = tid & 63;
  int base = tid * 8;
  int v[8]; int sum = 0;
#pragma unroll
  for (int i = 0; i < 8; ++i) {
    unsigned long long u = pk[base + i];
    v[i] = (int)(u >> 40);
    float degv = (float)(u & 0xFFFFFFFFFFull) * (1.f / 16777216.f);
    dinv[base + i] = rsqrtf(degv + 1.0f);
    sum += v[i];
  }
  int incl = sum;
#pragma unroll
  for (int d = 1; d < 64; d <<= 1) {
    int t = __shfl_up(incl, d, 64);
    if (lane >= d) incl += t;
  }
  if (lane == 63) wtot[wv] = incl;
  __syncthreads();
  if (wv == 0 && lane < 16) {
    int wval = wtot[lane];
    int wincl = wval;
#pragma unroll
    for (int d = 1; d < 16; d <<= 1) {
      int t = __shfl_up(wincl, d, 64);
      if (lane >= d) wincl += t;
    }
    wexcl[lane] = wincl - wval;
  }
  __syncthreads();
  int run = wexcl[wv] + (incl - sum);
#pragma unroll
  for (int i = 0; i < 8; ++i) {
    off[base + i] = run; pos[base + i] = run; run += v[i];
  }
  if (tid == 1023) off[8192] = run;
}

__global__ void scatter_k(const int* __restrict__ ei, const float* __restrict__ ew,
                          const float* __restrict__ dinv, int* __restrict__ pos,
                          int2* __restrict__ ed, int E) {
  int e = blockIdx.x * 256 + threadIdx.x;
  if (e >= E) return;
  int sidx = ei[e], d = ei[E + e];
  int p = atomicAdd(&pos[d], 1);
  int2 pay;
  pay.x = sidx;
  pay.y = __float_as_int(dinv[sidx] * ew[e] * dinv[d]);
  ed[p] = pay;
}

__global__ __launch_bounds__(512, 4)
void gather_mid_k(const int* __restrict__ off, const int2* __restrict__ ed,
                  const float* __restrict__ dinv, const float* __restrict__ hWa,
                  const float* __restrict__ bg1, const float* __restrict__ Wg2,
                  float* __restrict__ aggB) {
  __shared__ float wg[32 * 33];
  __shared__ float g1buf[16][33];
  int tid = threadIdx.x;
  for (int i = tid; i < 1024; i += 512) wg[(i >> 5) * 33 + (i & 31)] = Wg2[i];
  int nl = tid >> 5, j = tid & 31;
  int node = blockIdx.x * 16 + nl;
  float dv = dinv[node];
  float a0 = dv * dv * hWa[(size_t)node * 32 + j];
  float a1 = 0.f, a2 = 0.f, a3 = 0.f;
  int p0 = off[node], p1 = off[node + 1];
  int p = p0;
  for (; p + 3 < p1; p += 4) {
    int2 e0 = ed[p], e1 = ed[p + 1], e2 = ed[p + 2], e3 = ed[p + 3];
    a0 = fmaf(__int_as_float(e0.y), hWa[(size_t)e0.x * 32 + j], a0);
    a1 = fmaf(__int_as_float(e1.y), hWa[(size_t)e1.x * 32 + j], a1);
    a2 = fmaf(__int_as_float(e2.y), hWa[(size_t)e2.x * 32 + j], a2);
    a3 = fmaf(__int_as_float(e3.y), hWa[(size_t)e3.x * 32 + j], a3);
  }
  for (; p < p1; ++p) {
    int2 e0 = ed[p];
    a0 = fmaf(__int_as_float(e0.y), hWa[(size_t)e0.x * 32 + j], a0);
  }
  float v = (a0 + a1) + (a2 + a3) + bg1[j];
  g1buf[nl][j] = (v > 0.f) ? v : expm1f(v);
  __syncthreads();
  float acc = 0.f;
#pragma unroll
  for (int k = 0; k < 32; ++k) acc = fmaf(g1buf[nl][k], wg[k * 33 + j], acc);
  aggB[(size_t)node * 32 + j] = acc;
}

__global__ __launch_bounds__(512, 4)
void gather_final_k(const int* __restrict__ off, const int2* __restrict__ ed,
                    const float* __restrict__ dinv, const float* __restrict__ aggB,
                    const float* __restrict__ bg2, const float* __restrict__ h2o,
                    const float* __restrict__ Wfc, const float* __restrict__ bfc,
                    float* __restrict__ out) {
  int tid = threadIdx.x;
  int nl = tid >> 5, j = tid & 31;
  int node = blockIdx.x * 16 + nl;
  float dv = dinv[node];
  float a0 = dv * dv * aggB[(size_t)node * 32 + j];
  float a1 = 0.f, a2 = 0.f, a3 = 0.f;
  int p0 = off[node], p1 = off[node + 1];
  int p = p0;
  for (; p + 3 < p1; p += 4) {
    int2 e0 = ed[p], e1 = ed[p + 1], e2 = ed[p + 2], e3 = ed[p + 3];
    a0 = fmaf(__int_as_float(e0.y), aggB[(size_t)e0.x * 32 + j], a0);
    a1 = fmaf(__int_as_float(e1.y), aggB[(size_t)e1.x * 32 + j], a1);
    a2 = fmaf(__int_as_float(e2.y), aggB[(size_t)e2.x * 32 + j], a2);
    a3 = fmaf(__int_as_float(e3.y), aggB[(size_t)e3.x * 32 + j], a3);
  }
  for (; p < p1; ++p) {
    int2 e0 = ed[p];
    a0 = fmaf(__int_as_float(e0.y), aggB[(size_t)e0.x * 32 + j], a0);
  }
  float v = (a0 + a1) + (a2 + a3) + bg2[j];
  float e = (v > 0.f) ? v : expm1f(v);
  float h2v = h2o[(size_t)node * 32 + j];
  float p0s = h2v * Wfc[j];
  float p1s = h2v * Wfc[33 + j];
#pragma unroll
  for (int m = 1; m < 32; m <<= 1) {
    e   += __shfl_xor(e, m, 32);
    p0s += __shfl_xor(p0s, m, 32);
    p1s += __shfl_xor(p1s, m, 32);
  }
  if (j == 0) {
    float mean = e * (1.f / 32.f);
    float o0 = p0s + mean * Wfc[32] + bfc[0];
    float o1 = p1s + mean * Wfc[65] + bfc[1];
    float mx = fmaxf(o0, o1);
    float l = mx + logf(expf(o0 - mx) + expf(o1 - mx));
    out[node * 2 + 0] = o0 - l;
    out[node * 2 + 1] = o1 - l;
  }
}

extern "C" void kernel_launch(void* const* d_in, const int* in_sizes, int n_in,
                              void* d_out, int out_size, void* d_ws, size_t ws_size,
                              hipStream_t stream) {
  const float* x    = (const float*)d_in[0];
  const float* ew   = (const float*)d_in[1];
  const float* Wih1 = (const float*)d_in[2];
  const float* Whh1 = (const float*)d_in[3];
  const float* bih1 = (const float*)d_in[4];
  const float* bhh1 = (const float*)d_in[5];
  const float* ln_g = (const float*)d_in[6];
  const float* ln_b = (const float*)d_in[7];
  const float* Wih2 = (const float*)d_in[8];
  const float* Whh2 = (const float*)d_in[9];
  const float* bih2 = (const float*)d_in[10];
  const float* bhh2 = (const float*)d_in[11];
  const float* Wg1  = (const float*)d_in[12];
  const float* bg1  = (const float*)d_in[13];
  const float* Wg2  = (const float*)d_in[14];
  const float* bg2  = (const float*)d_in[15];
  const float* Wfc  = (const float*)d_in[16];
  const float* bfc  = (const float*)d_in[17];
  const int* ei     = (const int*)d_in[18];
  float* out = (float*)d_out;
  const int E = in_sizes[1];   // 262144

  float* ws   = (float*)d_ws;
  float* h2o  = ws;                    // 262144
  float* hWa  = ws + 262144;           // 262144
  float* aggB = ws + 524288;           // 262144
  unsigned long long* pk = (unsigned long long*)(ws + 786432);  // 8192 ull
  float* dinv = ws + 802816;           // 8192
  int*   off  = (int*)(ws + 811008);   // 8193
  int*   pos  = (int*)(ws + 819208);   // 8192
  int2*  ed   = (int2*)(ws + 827400);  // 262144 int2

  hipMemsetAsync((void*)pk, 0, 8192 * sizeof(unsigned long long), stream);

  MArgs m;
  m.x = x; m.Wih1 = Wih1; m.Whh1 = Whh1; m.bih1 = bih1; m.bhh1 = bhh1;
  m.ln_g = ln_g; m.ln_b = ln_b; m.Wih2 = Wih2; m.Whh2 = Whh2;
  m.bih2 = bih2; m.bhh2 = bhh2; m.Wg1 = Wg1; m.bg1 = bg1; m.Wg2 = Wg2;
  m.bg2 = bg2; m.Wfc = Wfc; m.bfc = bfc; m.ew = ew; m.ei = ei;
  m.pk = pk; m.dinv = dinv; m.h2o = h2o; m.hWa = hWa; m.aggB = aggB;
  m.out = out; m.off = off; m.pos = pos; m.ed = ed; m.E = E;

  void* kargs[] = { (void*)&m };
  hipError_t err = hipLaunchCooperativeKernel((const void*)mega_k, dim3(NNODES / 16),
                                              dim3(512), kargs, 0, stream);
  if (err != hipSuccess) {
    (void)hipGetLastError();   // clear; fall back to multi-launch path
    hipLaunchKernelGGL(count_k, dim3((E + 255) / 256), dim3(256), 0, stream, ei, ew, pk, E);
    hipLaunchKernelGGL(lstm_fused, dim3(NNODES / 16), dim3(512), 0, stream,
                       x, Wih1, Whh1, bih1, bhh1, ln_g, ln_b,
                       Wih2, Whh2, bih2, bhh2, Wg1, h2o, hWa);
    hipLaunchKernelGGL(scan_k, dim3(1), dim3(1024), 0, stream, pk, off, pos, dinv);
    hipLaunchKernelGGL(scatter_k, dim3((E + 255) / 256), dim3(256), 0, stream, ei, ew, dinv, pos, ed, E);
    hipLaunchKernelGGL(gather_mid_k, dim3(NNODES / 16), dim3(512), 0, stream,
                       off, ed, dinv, hWa, bg1, Wg2, aggB);
    hipLaunchKernelGGL(gather_final_k, dim3(NNODES / 16), dim3(512), 0, stream,
                       off, ed, dinv, aggB, bg2, h2o, Wfc, bfc, out);
  }
}

// Round 14
// 434.902 us; speedup vs baseline: 1.5505x; 1.5505x over previous
//
#include <hip/hip_runtime.h>

typedef __attribute__((ext_vector_type(8))) short short8;
typedef __attribute__((ext_vector_type(4))) float float4v;

#define NNODES 8192
#define SEQLEN 256

static __device__ __forceinline__ float bf2f(unsigned short u) {
  union { unsigned u; float f; } v; v.u = ((unsigned)u) << 16; return v.f;
}
static __device__ __forceinline__ unsigned short f2bf(float f) {
  union { float f; unsigned u; } v; v.f = f;
  unsigned r = v.u + 0x7FFFu + ((v.u >> 16) & 1u);
  return (unsigned short)(r >> 16);
}
static __device__ __forceinline__ void splitbf8(const float* v, short8& hi) {
#pragma unroll
  for (int j = 0; j < 8; ++j) hi[j] = (short)f2bf(v[j]);
}

// LSTM cell, log2-prescaled gates, merged-rcp: 5 exp2 + 3 rcp.
static __device__ __forceinline__ float lstm_cell(float zi, float zf, float zg,
                                                  float zo, float& c) {
  float ef = __builtin_amdgcn_exp2f(-zf);
  float ei = __builtin_amdgcn_exp2f(-zi);
  float eg = __builtin_amdgcn_exp2f(fminf(zg + zg, 60.f));
  float fterm = c * __builtin_amdgcn_rcpf(1.f + ef);
  float igt = (eg - 1.f) * __builtin_amdgcn_rcpf((1.f + ei) * (eg + 1.f));
  c = fterm + igt;
  float eo = __builtin_amdgcn_exp2f(-zo);
  float ec = __builtin_amdgcn_exp2f(fminf(2.88539008178f * c, 40.f));
  return (ec - 1.f) * __builtin_amdgcn_rcpf((1.f + eo) * (ec + 1.f));
}

// v14 == v12 (best measured: 435 us). Coop mega-kernel (v13) regressed:
// grid.sync flushes caches (FETCH 4.4->16 MB, WRITE 2->27 MB) — reverted.
__global__ __launch_bounds__(512, 4)
void lstm_fused(const float* __restrict__ x,
                const float* __restrict__ Wih1, const float* __restrict__ Whh1,
                const float* __restrict__ bih1, const float* __restrict__ bhh1,
                const float* __restrict__ ln_g, const float* __restrict__ ln_b,
                const float* __restrict__ Wih2, const float* __restrict__ Whh2,
                const float* __restrict__ bih2, const float* __restrict__ bhh2,
                const float* __restrict__ Wg1,
                float* __restrict__ h2out, float* __restrict__ hWa)
{
  const int tid = threadIdx.x;
  const int w = tid >> 6;
  const int lane = tid & 63;
  const int c = lane & 15;
  const int q = lane >> 4;
  const int cn = lane >> 2;
  const int ch = lane & 3;
  const int hid = w * 4 + ch;
  const int nodeBase = blockIdx.x * 16;
  const float L = 1.44269504089f;

  __shared__ __align__(16) float xlds[16 * 260];
  __shared__ __align__(16) float zbuf1[16 * 132];
  __shared__ __align__(16) float zbuf2[16 * 132];
  __shared__ __align__(16) unsigned short h1p[2][16 * 40];
  __shared__ __align__(16) unsigned short h2p[2][16 * 40];
  __shared__ __align__(16) float mu2[32];
  __shared__ __align__(16) float wgbuf[32 * 33];
  __shared__ __align__(16) float h2f[16 * 33];

  for (int i = tid; i < 16 * 256; i += 512) {
    int nn = i >> 8, tt = i & 255;
    xlds[nn * 260 + tt] = x[(size_t)(nodeBase + nn) * SEQLEN + tt];
  }
  if (tid < 64) xlds[(tid >> 2) * 260 + 256 + (tid & 3)] = 0.f;
  for (int i = tid; i < 1024; i += 512) wgbuf[(i >> 5) * 33 + (i & 31)] = Wg1[i];

  const int brow = (c & 3) * 32 + w * 4 + (c >> 2);
  short8 Bh1, Bi2, Bh2;
  float Gpre, b1pre, b2pre;
  {
    float v[8];
#pragma unroll
    for (int j = 0; j < 8; ++j) v[j] = L * Whh1[brow * 32 + q * 8 + j];
    splitbf8(v, Bh1);
#pragma unroll
    for (int j = 0; j < 8; ++j) v[j] = L * Wih2[brow * 32 + q * 8 + j] * ln_g[q * 8 + j];
    splitbf8(v, Bi2);
#pragma unroll
    for (int j = 0; j < 8; ++j) v[j] = L * Whh2[brow * 32 + q * 8 + j];
    splitbf8(v, Bh2);
    float sG = 0.f, sB = 0.f;
    for (int k = 0; k < 32; ++k) {
      sG += Wih2[brow * 32 + k] * ln_g[k];
      sB += Wih2[brow * 32 + k] * ln_b[k];
    }
    Gpre = L * sG;
    b1pre = L * (bih1[brow] + bhh1[brow]);
    b2pre = L * (sB + bih2[brow] + bhh2[brow]);
  }
  const float4v C1 = {b1pre, b1pre, b1pre, b1pre};
  const float4v C2 = {b2pre, b2pre, b2pre, b2pre};
  const float4v z4 = {0.f, 0.f, 0.f, 0.f};
  float w1v[4];
#pragma unroll
  for (int g = 0; g < 4; ++g) w1v[g] = L * Wih1[g * 32 + hid];

  int zW[4];
#pragma unroll
  for (int r = 0; r < 4; ++r) zW[r] = (q * 4 + r) * 132 + w * 16 + c;
  const int zR = cn * 132 + hid * 4;
  const int hWr = cn * 40 + hid;
  const int hRd = c * 40 + q * 8;

  short8 h1A = {0,0,0,0,0,0,0,0};
  short8 h2A = {0,0,0,0,0,0,0,0};
  float c1 = 0.f, c2 = 0.f, hv2 = 0.f;
  __syncthreads();

  // ---- prologue: cell1(0) -> h1p[1] ----
  {
    float4v za = __builtin_amdgcn_mfma_f32_16x16x32_bf16(h1A, Bh1, C1, 0, 0, 0);
#pragma unroll
    for (int r = 0; r < 4; ++r) zbuf1[zW[r]] = za[r];
    float4v zv = *(const float4v*)&zbuf1[zR];
    float xv = xlds[cn * 260 + 0];
    float hv = lstm_cell(fmaf(xv, w1v[0], zv[0]), fmaf(xv, w1v[1], zv[1]),
                         fmaf(xv, w1v[2], zv[2]), fmaf(xv, w1v[3], zv[3]), c1);
    h1p[1][hWr] = f2bf(hv);
  }
  __syncthreads();
  h1A = *(const short8*)&h1p[1][hRd];

  for (int t = 0; t < SEQLEN; ++t) {
    const int pl = t & 1;
    float4v za = __builtin_amdgcn_mfma_f32_16x16x32_bf16(h1A, Bh1, C1, 0, 0, 0);
    float4v db = __builtin_amdgcn_mfma_f32_16x16x32_bf16(h2A, Bh2, C2, 0, 0, 0);

    float s = 0.f, s2 = 0.f;
#pragma unroll
    for (int j = 0; j < 8; ++j) {
      float hf = bf2f((unsigned short)h1A[j]);
      s += hf; s2 = fmaf(hf, hf, s2);
    }
    s  += __shfl_xor(s, 16, 64);  s  += __shfl_xor(s, 32, 64);
    s2 += __shfl_xor(s2, 16, 64); s2 += __shfl_xor(s2, 32, 64);
    float mu = s * (1.f / 32.f);
    float var = s2 * (1.f / 32.f) - mu * mu;
    float rstd = rsqrtf(var + 1e-5f);
    if (q < 2) mu2[c * 2 + q] = (q == 0) ? rstd : rstd * mu;

    float4v da = __builtin_amdgcn_mfma_f32_16x16x32_bf16(h1A, Bi2, z4, 0, 0, 0);
#pragma unroll
    for (int r = 0; r < 4; ++r) {
      float2 ab = *(const float2*)&mu2[(q * 4 + r) * 2];
      zbuf2[zW[r]] = fmaf(ab.x, da[r], fmaf(-ab.y, Gpre, db[r]));
      zbuf1[zW[r]] = za[r];
    }
    {
      float4v zv = *(const float4v*)&zbuf2[zR];
      hv2 = lstm_cell(zv[0], zv[1], zv[2], zv[3], c2);
      h2p[pl][hWr] = f2bf(hv2);
    }
    {
      float4v zv = *(const float4v*)&zbuf1[zR];
      float xv = xlds[cn * 260 + t + 1];
      float hv = lstm_cell(fmaf(xv, w1v[0], zv[0]), fmaf(xv, w1v[1], zv[1]),
                           fmaf(xv, w1v[2], zv[2]), fmaf(xv, w1v[3], zv[3]), c1);
      h1p[pl][hWr] = f2bf(hv);
    }
    __syncthreads();
    h1A = *(const short8*)&h1p[pl][hRd];
    h2A = *(const short8*)&h2p[pl][hRd];
  }

  h2out[(size_t)(nodeBase + cn) * 32 + hid] = hv2;

  __syncthreads();
  h2f[cn * 33 + hid] = hv2;
  __syncthreads();
  {
    int nl = tid >> 5, j = tid & 31;
    float acc = 0.f;
#pragma unroll
    for (int k = 0; k < 32; ++k) acc = fmaf(h2f[nl * 33 + k], wgbuf[k * 33 + j], acc);
    hWa[(size_t)(nodeBase + nl) * 32 + j] = acc;
  }
}

// ---------------- GCN ----------------
// packed count: one 64-bit atomic per edge. {count:24b | deg:40b fix2^-24}
__global__ void count_k(const int* __restrict__ ei, const float* __restrict__ ew,
                        unsigned long long* __restrict__ pk, int E) {
  int e = blockIdx.x * 256 + threadIdx.x;
  if (e >= E) return;
  int d = ei[E + e];
  unsigned long long pay = (1ull << 40) |
      (unsigned long long)(unsigned)(ew[e] * 16777216.f + 0.5f);
  atomicAdd(&pk[d], pay);
}

// wave-shuffle hierarchical scan: 2 barriers
__global__ __launch_bounds__(1024, 1)
void scan_k(const unsigned long long* __restrict__ pk, int* __restrict__ off,
            int* __restrict__ pos, float* __restrict__ dinv) {
  __shared__ int wtot[16];
  __shared__ int wexcl[16];
  int tid = threadIdx.x;
  int wv = tid >> 6, lane = tid & 63;
  int base = tid * 8;
  int v[8]; int sum = 0;
#pragma unroll
  for (int i = 0; i < 8; ++i) {
    unsigned long long u = pk[base + i];
    v[i] = (int)(u >> 40);
    float degv = (float)(u & 0xFFFFFFFFFFull) * (1.f / 16777216.f);
    dinv[base + i] = rsqrtf(degv + 1.0f);
    sum += v[i];
  }
  int incl = sum;
#pragma unroll
  for (int d = 1; d < 64; d <<= 1) {
    int t = __shfl_up(incl, d, 64);
    if (lane >= d) incl += t;
  }
  if (lane == 63) wtot[wv] = incl;
  __syncthreads();
  if (wv == 0 && lane < 16) {
    int wval = wtot[lane];
    int wincl = wval;
#pragma unroll
    for (int d = 1; d < 16; d <<= 1) {
      int t = __shfl_up(wincl, d, 64);
      if (lane >= d) wincl += t;
    }
    wexcl[lane] = wincl - wval;
  }
  __syncthreads();
  int run = wexcl[wv] + (incl - sum);
#pragma unroll
  for (int i = 0; i < 8; ++i) {
    off[base + i] = run; pos[base + i] = run; run += v[i];
  }
  if (tid == 1023) off[8192] = run;
}

__global__ void scatter_k(const int* __restrict__ ei, const float* __restrict__ ew,
                          const float* __restrict__ dinv, int* __restrict__ pos,
                          int2* __restrict__ ed, int E) {
  int e = blockIdx.x * 256 + threadIdx.x;
  if (e >= E) return;
  int sidx = ei[e], d = ei[E + e];
  int p = atomicAdd(&pos[d], 1);
  int2 pay;
  pay.x = sidx;
  pay.y = __float_as_int(dinv[sidx] * ew[e] * dinv[d]);
  ed[p] = pay;
}

// conv1 gather (unroll-4) + elu + (g1 @ Wg2); 16 nodes/block
__global__ __launch_bounds__(512, 4)
void gather_mid_k(const int* __restrict__ off, const int2* __restrict__ ed,
                  const float* __restrict__ dinv, const float* __restrict__ hWa,
                  const float* __restrict__ bg1, const float* __restrict__ Wg2,
                  float* __restrict__ aggB) {
  __shared__ float wg[32 * 33];
  __shared__ float g1buf[16][33];
  int tid = threadIdx.x;
  for (int i = tid; i < 1024; i += 512) wg[(i >> 5) * 33 + (i & 31)] = Wg2[i];
  int nl = tid >> 5, j = tid & 31;
  int node = blockIdx.x * 16 + nl;
  float dv = dinv[node];
  float a0 = dv * dv * hWa[(size_t)node * 32 + j];
  float a1 = 0.f, a2 = 0.f, a3 = 0.f;
  int p0 = off[node], p1 = off[node + 1];
  int p = p0;
  for (; p + 3 < p1; p += 4) {
    int2 e0 = ed[p], e1 = ed[p + 1], e2 = ed[p + 2], e3 = ed[p + 3];
    a0 = fmaf(__int_as_float(e0.y), hWa[(size_t)e0.x * 32 + j], a0);
    a1 = fmaf(__int_as_float(e1.y), hWa[(size_t)e1.x * 32 + j], a1);
    a2 = fmaf(__int_as_float(e2.y), hWa[(size_t)e2.x * 32 + j], a2);
    a3 = fmaf(__int_as_float(e3.y), hWa[(size_t)e3.x * 32 + j], a3);
  }
  for (; p < p1; ++p) {
    int2 e0 = ed[p];
    a0 = fmaf(__int_as_float(e0.y), hWa[(size_t)e0.x * 32 + j], a0);
  }
  float v = (a0 + a1) + (a2 + a3) + bg1[j];
  g1buf[nl][j] = (v > 0.f) ? v : expm1f(v);
  __syncthreads();
  float acc = 0.f;
#pragma unroll
  for (int k = 0; k < 32; ++k) acc = fmaf(g1buf[nl][k], wg[k * 33 + j], acc);
  aggB[(size_t)node * 32 + j] = acc;
}

// conv2 gather (unroll-4) + elu + mean + fc + log-softmax; 16 nodes/block
__global__ __launch_bounds__(512, 4)
void gather_final_k(const int* __restrict__ off, const int2* __restrict__ ed,
                    const float* __restrict__ dinv, const float* __restrict__ aggB,
                    const float* __restrict__ bg2, const float* __restrict__ h2o,
                    const float* __restrict__ Wfc, const float* __restrict__ bfc,
                    float* __restrict__ out) {
  int tid = threadIdx.x;
  int nl = tid >> 5, j = tid & 31;
  int node = blockIdx.x * 16 + nl;
  float dv = dinv[node];
  float a0 = dv * dv * aggB[(size_t)node * 32 + j];
  float a1 = 0.f, a2 = 0.f, a3 = 0.f;
  int p0 = off[node], p1 = off[node + 1];
  int p = p0;
  for (; p + 3 < p1; p += 4) {
    int2 e0 = ed[p], e1 = ed[p + 1], e2 = ed[p + 2], e3 = ed[p + 3];
    a0 = fmaf(__int_as_float(e0.y), aggB[(size_t)e0.x * 32 + j], a0);
    a1 = fmaf(__int_as_float(e1.y), aggB[(size_t)e1.x * 32 + j], a1);
    a2 = fmaf(__int_as_float(e2.y), aggB[(size_t)e2.x * 32 + j], a2);
    a3 = fmaf(__int_as_float(e3.y), aggB[(size_t)e3.x * 32 + j], a3);
  }
  for (; p < p1; ++p) {
    int2 e0 = ed[p];
    a0 = fmaf(__int_as_float(e0.y), aggB[(size_t)e0.x * 32 + j], a0);
  }
  float v = (a0 + a1) + (a2 + a3) + bg2[j];
  float e = (v > 0.f) ? v : expm1f(v);
  float h2v = h2o[(size_t)node * 32 + j];
  float p0s = h2v * Wfc[j];
  float p1s = h2v * Wfc[33 + j];
#pragma unroll
  for (int m = 1; m < 32; m <<= 1) {
    e   += __shfl_xor(e, m, 32);
    p0s += __shfl_xor(p0s, m, 32);
    p1s += __shfl_xor(p1s, m, 32);
  }
  if (j == 0) {
    float mean = e * (1.f / 32.f);
    float o0 = p0s + mean * Wfc[32] + bfc[0];
    float o1 = p1s + mean * Wfc[65] + bfc[1];
    float mx = fmaxf(o0, o1);
    float l = mx + logf(expf(o0 - mx) + expf(o1 - mx));
    out[node * 2 + 0] = o0 - l;
    out[node * 2 + 1] = o1 - l;
  }
}

extern "C" void kernel_launch(void* const* d_in, const int* in_sizes, int n_in,
                              void* d_out, int out_size, void* d_ws, size_t ws_size,
                              hipStream_t stream) {
  const float* x    = (const float*)d_in[0];
  const float* ew   = (const float*)d_in[1];
  const float* Wih1 = (const float*)d_in[2];
  const float* Whh1 = (const float*)d_in[3];
  const float* bih1 = (const float*)d_in[4];
  const float* bhh1 = (const float*)d_in[5];
  const float* ln_g = (const float*)d_in[6];
  const float* ln_b = (const float*)d_in[7];
  const float* Wih2 = (const float*)d_in[8];
  const float* Whh2 = (const float*)d_in[9];
  const float* bih2 = (const float*)d_in[10];
  const float* bhh2 = (const float*)d_in[11];
  const float* Wg1  = (const float*)d_in[12];
  const float* bg1  = (const float*)d_in[13];
  const float* Wg2  = (const float*)d_in[14];
  const float* bg2  = (const float*)d_in[15];
  const float* Wfc  = (const float*)d_in[16];
  const float* bfc  = (const float*)d_in[17];
  const int* ei     = (const int*)d_in[18];
  float* out = (float*)d_out;
  const int E = in_sizes[1];   // 262144

  float* ws   = (float*)d_ws;
  float* h2o  = ws;                    // 262144
  float* hWa  = ws + 262144;           // 262144
  float* aggB = ws + 524288;           // 262144
  unsigned long long* pk = (unsigned long long*)(ws + 786432);  // 8192 ull
  float* dinv = ws + 802816;           // 8192
  int*   off  = (int*)(ws + 811008);   // 8193
  int*   pos  = (int*)(ws + 819208);   // 8192
  int2*  ed   = (int2*)(ws + 827400);  // 262144 int2

  hipMemsetAsync((void*)pk, 0, 8192 * sizeof(unsigned long long), stream);
  hipLaunchKernelGGL(count_k, dim3((E + 255) / 256), dim3(256), 0, stream, ei, ew, pk, E);
  hipLaunchKernelGGL(lstm_fused, dim3(NNODES / 16), dim3(512), 0, stream,
                     x, Wih1, Whh1, bih1, bhh1, ln_g, ln_b,
                     Wih2, Whh2, bih2, bhh2, Wg1, h2o, hWa);
  hipLaunchKernelGGL(scan_k, dim3(1), dim3(1024), 0, stream, pk, off, pos, dinv);
  hipLaunchKernelGGL(scatter_k, dim3((E + 255) / 256), dim3(256), 0, stream, ei, ew, dinv, pos, ed, E);
  hipLaunchKernelGGL(gather_mid_k, dim3(NNODES / 16), dim3(512), 0, stream,
                     off, ed, dinv, hWa, bg1, Wg2, aggB);
  hipLaunchKernelGGL(gather_final_k, dim3(NNODES / 16), dim3(512), 0, stream,
                     off, ed, dinv, aggB, bg2, h2o, Wfc, bfc, out);
}